// Round 4
// baseline (80.498 us; speedup 1.0000x reference)
//
#include <hip/hip_runtime.h>

// dfm: 10-feature FM layer. x_i are dense one-hot (1024 x v_i) fp32; w_i (v_i x 64) fp32.
// out (1024 x 704) fp32 = [0.5*(sum(emb)^2 - sum(emb^2)) | emb0 .. emb9]
// One-hot => dot(x,w) == val*w[idx] exactly; dot(x^2,w^2) == val^2*w[idx]^2.
//
// R3: chain-length balancing. Waves-per-row scaled to vocab so the worst
// dependent load->check chain is ~13 rounds everywhere, hiding the latency
// tail under the bulk-BW phase. 512-thread blocks:
//   f0,f1: 8 waves/row (block-per-row)     chain 13 / 7
//   f2:    4 waves/row (2 rows/block)      chain 5
//   f3:    2 waves/row (4 rows/block)      chain 3
//   f4-f9: 1 wave/row  (8 rows/block)      chain <=5
// Early exit: volatile LDS flag per row-group (no barriers in loop) + __ballot.

#define NF 10
#define BATCHN 1024
#define EMBD 64

constexpr int VOC[NF] = {100000, 50000, 20000, 10000, 5000, 2000, 1000, 500, 200, 100};
// all VOC divisible by 4 -> float4 loads never straddle the row end

struct XPtrs { const float* x[NF]; };
struct WPtrs { const float* w[NF]; };

typedef float v4f __attribute__((ext_vector_type(4)));

__device__ __forceinline__ v4f ntload4(const float* p) {
  return __builtin_nontemporal_load(reinterpret_cast<const v4f*>(p));
}

// Scans one 4KB chunk (1024 floats starting at j0): 4 x float4 per lane, 256 apart.
// Returns wave-uniform "found in this chunk"; finder lane writes (idx,val).
__device__ __forceinline__ bool scan_chunk(const float* rp, int v, int j0, int lane,
                                           int slot, int* __restrict__ idx_out,
                                           float* __restrict__ val_out) {
  v4f q[4];
#pragma unroll
  for (int s = 0; s < 4; ++s) {
    const int j = j0 + s * 256 + lane * 4;
    if (j < v) q[s] = ntload4(rp + j);
    else       q[s] = (v4f){0.f, 0.f, 0.f, 0.f};
  }
  bool flag = false;
#pragma unroll
  for (int s = 0; s < 4; ++s)
    flag |= (q[s][0] != 0.f) | (q[s][1] != 0.f) | (q[s][2] != 0.f) | (q[s][3] != 0.f);
  if (__ballot(flag)) {
    if (flag) {
#pragma unroll
      for (int s = 0; s < 4; ++s) {
#pragma unroll
        for (int c = 0; c < 4; ++c) {
          if (q[s][c] != 0.f) {
            idx_out[slot] = j0 + s * 256 + lane * 4 + c;
            val_out[slot] = q[s][c];
          }
        }
      }
    }
    return true;
  }
  return false;
}

// W waves cooperatively scan one row of feature F; early exit via volatile LDS flag.
template <int F, int W>
__device__ __forceinline__ void scan_multi(const float* __restrict__ xbase, int row,
                                           int w, int lane, volatile int* flag,
                                           int* __restrict__ idx_out,
                                           float* __restrict__ val_out) {
  const int v   = VOC[F];
  const int nch = (v + 1023) >> 10;
  const float* rp = xbase + (size_t)row * v;
  const int slot = F * BATCHN + row;
  for (int k = w; k < nch; k += W) {
    if (scan_chunk(rp, v, k << 10, lane, slot, idx_out, val_out)) {
      *flag = 1;
      return;
    }
    if (W > 1 && *flag) return;   // sibling wave found it
  }
}

// Single wave scans one row of feature F (no flag needed).
template <int F>
__device__ __forceinline__ void scan_wave(const float* __restrict__ xbase, int row,
                                          int lane, int* __restrict__ idx_out,
                                          float* __restrict__ val_out) {
  const int v   = VOC[F];
  const int nch = (v + 1023) >> 10;
  const float* rp = xbase + (size_t)row * v;
  const int slot = F * BATCHN + row;
  for (int k = 0; k < nch; ++k)
    if (scan_chunk(rp, v, k << 10, lane, slot, idx_out, val_out)) return;
}

#define GRID_F01   2048   // f0,f1: block-per-row
#define GRID_F2    512    // f2: 2 rows/block
#define GRID_F3    256    // f3: 4 rows/block
#define GRID_SMALL 768    // f4..f9: 8 rows/block (6144 waves)
#define TOTAL_BLOCKS (GRID_F01 + GRID_F2 + GRID_F3 + GRID_SMALL)  // 3584

__global__ __launch_bounds__(512) void scan_onehot(XPtrs p,
                                                   int* __restrict__ idx_out,
                                                   float* __restrict__ val_out) {
  const int blk  = blockIdx.x;
  const int tid  = threadIdx.x;
  const int wid  = tid >> 6;
  const int lane = tid & 63;

  __shared__ volatile int flags[8];
  if (tid < 8) flags[tid] = 0;
  __syncthreads();

  if (blk < GRID_F01) {
    const int row = blk & 1023;
    if (blk < 1024) scan_multi<0, 8>(p.x[0], row, wid, lane, &flags[0], idx_out, val_out);
    else            scan_multi<1, 8>(p.x[1], row, wid, lane, &flags[0], idx_out, val_out);
  } else if (blk < GRID_F01 + GRID_F2) {
    const int grp = wid >> 2;                       // 0..1
    const int row = (blk - GRID_F01) * 2 + grp;
    scan_multi<2, 4>(p.x[2], row, wid & 3, lane, &flags[grp], idx_out, val_out);
  } else if (blk < GRID_F01 + GRID_F2 + GRID_F3) {
    const int grp = wid >> 1;                       // 0..3
    const int row = (blk - GRID_F01 - GRID_F2) * 4 + grp;
    scan_multi<3, 2>(p.x[3], row, wid & 1, lane, &flags[grp], idx_out, val_out);
  } else {
    const int widx = ((blk - GRID_F01 - GRID_F2 - GRID_F3) << 3) + wid;  // 0..6143
    const int f    = 4 + (widx >> 10);
    const int row  = widx & 1023;
    switch (f) {
      case 4: scan_wave<4>(p.x[4], row, lane, idx_out, val_out); break;
      case 5: scan_wave<5>(p.x[5], row, lane, idx_out, val_out); break;
      case 6: scan_wave<6>(p.x[6], row, lane, idx_out, val_out); break;
      case 7: scan_wave<7>(p.x[7], row, lane, idx_out, val_out); break;
      case 8: scan_wave<8>(p.x[8], row, lane, idx_out, val_out); break;
      case 9: scan_wave<9>(p.x[9], row, lane, idx_out, val_out); break;
    }
  }
}

// grid = 1024 (one block per batch row), block = 64 (one thread per emb dim).
// Accumulation order matches the reference (sequential i = 0..9).
__global__ __launch_bounds__(64) void emit_fm(WPtrs wp,
                                              const int* __restrict__ idx,
                                              const float* __restrict__ val,
                                              float* __restrict__ out) {
  const int b = blockIdx.x;
  const int d = threadIdx.x;
  float s = 0.0f, q = 0.0f;
  float e[NF];
#pragma unroll
  for (int i = 0; i < NF; ++i) {
    const int   ix = idx[i * BATCHN + b];
    const float vv = val[i * BATCHN + b];
    const float wv = wp.w[i][(size_t)ix * EMBD + d];
    const float ev = vv * wv;
    e[i] = ev;
    s += ev;
    q += (vv * vv) * (wv * wv);   // x^2 . w^2
  }
  float* o = out + (size_t)b * ((NF + 1) * EMBD);
  o[d] = 0.5f * (s * s - q);
#pragma unroll
  for (int i = 0; i < NF; ++i) {
    o[(i + 1) * EMBD + d] = e[i];
  }
}

extern "C" void kernel_launch(void* const* d_in, const int* in_sizes, int n_in,
                              void* d_out, int out_size, void* d_ws, size_t ws_size,
                              hipStream_t stream) {
  XPtrs xp;
  WPtrs wp;
  for (int i = 0; i < NF; ++i) {
    xp.x[i] = (const float*)d_in[2 * i];       // x_i
    wp.w[i] = (const float*)d_in[2 * i + 1];   // w_i
  }
  int*   idx = (int*)d_ws;
  float* val = (float*)((char*)d_ws + (size_t)NF * BATCHN * sizeof(int));

  scan_onehot<<<TOTAL_BLOCKS, 512, 0, stream>>>(xp, idx, val);
  emit_fm<<<BATCHN, 64, 0, stream>>>(wp, idx, val, (float*)d_out);
}